// Round 3
// baseline (159.222 us; speedup 1.0000x reference)
//
#include <hip/hip_runtime.h>

typedef __attribute__((ext_vector_type(4))) int  i32x4;
typedef __attribute__((ext_vector_type(16))) int i32x16;

#define IC   256
#define OCH  128
#define BSZ  16
#define IH   64
#define IW   64
#define OH2  128
#define OW2  128
#define QMAXF 127.0f

// ws float-offset layout
#define WS_WSCALE 0        // 256 per-ic weight absmax
#define WS_APART  256      // 8*256 per-(bq,ic) act absmax partials
#define WS_QS     2304     // 256: x multiplier 1/(sc*sx)
#define WS_WQS    2560     // 256: w multiplier sc/sw
#define WS_F      2816     // sx*sw
#define WS_WQ8    3072     // int8 [9][16][128][16] quantized weights (294912 B)

// ---------------- K1: per-channel absmax (partials over batch) ----------------
__global__ __launch_bounds__(256) void k_channel_scales(
        const float* __restrict__ x, const float* __restrict__ w,
        float* __restrict__ ws) {
    const int ic = blockIdx.x;
    const int bq = blockIdx.y;          // 0..7, two batches each
    const int t  = threadIdx.x;
    float amax = 0.f, wmax = 0.f;
    for (int bb = 2 * bq; bb < 2 * bq + 2; ++bb) {
        const float* xp = x + ((size_t)(bb * IC + ic)) * (IH * IW);
        for (int hw = t * 4; hw < IH * IW; hw += 1024) {
            float4 v = *(const float4*)(xp + hw);
            amax = fmaxf(amax, fmaxf(fmaxf(fabsf(v.x), fabsf(v.y)),
                                     fmaxf(fabsf(v.z), fabsf(v.w))));
        }
    }
    if (bq == 0)
        for (int j = t; j < OCH * 9; j += 256)
            wmax = fmaxf(wmax, fabsf(w[ic * (OCH * 9) + j]));
    __shared__ float r1[256], r2[256];
    r1[t] = wmax; r2[t] = amax;
    __syncthreads();
    for (int s = 128; s > 0; s >>= 1) {
        if (t < s) {
            r1[t] = fmaxf(r1[t], r1[t + s]);
            r2[t] = fmaxf(r2[t], r2[t + s]);
        }
        __syncthreads();
    }
    if (t == 0) {
        ws[WS_APART + bq * 256 + ic] = r2[0];
        if (bq == 0) ws[WS_WSCALE + ic] = r1[0];
    }
}

// ---------------- K2: scales + per-tensor quant steps ----------------
__global__ __launch_bounds__(256) void k_finalize(float* __restrict__ ws) {
    const int t = threadIdx.x;          // = ic
    float asc = 0.f;
    for (int q = 0; q < 8; ++q) asc = fmaxf(asc, ws[WS_APART + q * 256 + t]);
    const float wsc = ws[WS_WSCALE + t];
    float sc = sqrtf(asc) / sqrtf(wsc);
    if (sc == 0.f) sc = 1.f;
    float wm = wsc * sc;                // elementwise max of |w*sc| (monotone)
    float am = asc / sc;                // elementwise max of |x/sc|
    __shared__ float r1[256], r2[256];
    r1[t] = wm; r2[t] = am;
    __syncthreads();
    for (int s = 128; s > 0; s >>= 1) {
        if (t < s) {
            r1[t] = fmaxf(r1[t], r1[t + s]);
            r2[t] = fmaxf(r2[t], r2[t + s]);
        }
        __syncthreads();
    }
    float sw = r1[0] / QMAXF; if (sw == 0.f) sw = 1.f;
    float sx = r2[0] / QMAXF; if (sx == 0.f) sx = 1.f;
    ws[WS_QS  + t] = 1.f / (sc * sx);
    ws[WS_WQS + t] = sc / sw;
    if (t == 0) ws[WS_F] = sx * sw;
}

// ---------------- K3: quantize weights -> int8 [tap][kq][oc][16] ----------------
__global__ __launch_bounds__(256) void k_quant_w(
        const float* __restrict__ w, float* __restrict__ ws) {
    const int idx = blockIdx.x * 256 + threadIdx.x;   // [tap][kq][oc][e4]
    const int e0  = (idx & 3) * 4;
    const int oc  = (idx >> 2) & 127;
    const int kq  = (idx >> 9) & 15;
    const int tap = idx >> 13;
    unsigned pack = 0;
    #pragma unroll
    for (int c = 0; c < 4; ++c) {
        const int ic = kq * 16 + e0 + c;
        float q = rintf(w[((size_t)ic * OCH + oc) * 9 + tap] * ws[WS_WQS + ic]);
        q = fminf(fmaxf(q, -128.f), 127.f);
        pack |= ((unsigned)((int)q & 255)) << (8 * c);
    }
    ((unsigned*)(ws + WS_WQ8))[idx] = pack;           // byte offset = idx*4 matches layout
}

// ---------------- K4: MFMA implicit-GEMM conv with K-folded taps ----------------
// A-tile: int8 [r(2)][lv(33)][ic(256)], byte = (r*33+lv)*256 + (ic ^ ((lv&15)<<4))
__device__ __forceinline__ i32x4 load_a(const char* qa, int R, int S, int ks, int lane) {
    const int lv = (lane & 31) + S;
    const unsigned byte = (unsigned)((R * 33 + lv) * 256)
        + (((unsigned)(ks * 32 + ((lane >> 5) << 4))) ^ (((unsigned)(lv & 15)) << 4));
    return *(const i32x4*)(qa + byte);
}

__device__ __forceinline__ i32x4 load_b(const char* wq8, int tap, int ks, int oc, int lane) {
    const size_t off = ((size_t)((tap * 16 + ks * 2 + (lane >> 5)) * OCH + oc)) * 16;
    return *(const i32x4*)(wq8 + off);
}

template<int NN, int NT>
__device__ __forceinline__ void gemm_run(const char* qa, const char* wq8,
        const int (&taps)[NT], int ocb, int lane, i32x16 (&acc)[NN]) {
    const int oc0 = ocb + (lane & 31);
    int R0 = taps[0] < 3 ? 1 : 0, S0 = (taps[0] % 3 == 0) ? 1 : 0;
    i32x4 a = load_a(qa, R0, S0, 0, lane);
    i32x4 b[NN];
    #pragma unroll
    for (int n = 0; n < NN; ++n) b[n] = load_b(wq8, taps[0], 0, oc0 + n * 32, lane);
    #pragma unroll
    for (int g = 0; g < NT * 8; ++g) {
        i32x4 a_n; i32x4 b_n[NN];
        if (g + 1 < NT * 8) {
            const int tap = taps[(g + 1) >> 3];
            const int R = tap < 3 ? 1 : 0, S = (tap % 3 == 0) ? 1 : 0;
            a_n = load_a(qa, R, S, (g + 1) & 7, lane);
            #pragma unroll
            for (int n = 0; n < NN; ++n)
                b_n[n] = load_b(wq8, tap, (g + 1) & 7, oc0 + n * 32, lane);
        }
        #pragma unroll
        for (int n = 0; n < NN; ++n)
            acc[n] = __builtin_amdgcn_mfma_i32_32x32x32_i8(a, b[n], acc[n], 0, 0, 0);
        a = a_n;
        #pragma unroll
        for (int n = 0; n < NN; ++n) b[n] = b_n[n];
    }
}

// C/D layout (m74/m101): col = lane&31 (=oc offset), row(v) = (reg&3)+8*(reg>>2)+4*(lane>>5)
__device__ __forceinline__ void dump_acc(int* buf, const i32x16& a, int oc, int par, int lane) {
    const int vb = 4 * (lane >> 5);
    #pragma unroll
    for (int reg = 0; reg < 16; ++reg) {
        const int v = (reg & 3) + 8 * (reg >> 2) + vb;
        buf[oc * 66 + 2 * v + par] = a[reg];
    }
}

__global__ __launch_bounds__(576) void k_conv(
        const float* __restrict__ x, const float* __restrict__ bias,
        const float* __restrict__ ws, float* __restrict__ out) {
    __shared__ char smem[16896 + 2 * 33792 + 1024];
    char* qa   = smem;
    int*  buf0 = (int*)(smem + 16896);            // oh = 2u:   [128 oc][66]
    int*  buf1 = (int*)(smem + 16896 + 33792);    // oh = 2u+1: [128 oc][66]
    float* sqs = (float*)(smem + 16896 + 2 * 33792);

    const int tid  = threadIdx.x;
    const int u    = blockIdx.x;     // output rows 2u, 2u+1
    const int vh   = blockIdx.y;     // column half: v in [32*vh, 32*vh+31]
    const int b    = blockIdx.z;
    const int vbase = vh * 32;
    const int lane = tid & 63;
    const int wid  = tid >> 6;       // 0..8

    if (tid < 256) sqs[tid] = ws[WS_QS + tid];
    __syncthreads();

    // stage + quantize x rows u, u+1 (cols vbase..vbase+32) -> int8 LDS, swizzled
    for (int j = tid; j < 2 * 33 * 256; j += 576) {
        const int lv  = j % 33;
        const int t2  = j / 33;
        const int ic  = t2 & 255;
        const int r   = t2 >> 8;
        const int row = u + r;
        const int col = vbase + lv;
        float val = 0.f;
        if (row < IH && col < IW)
            val = x[(((size_t)(b * IC + ic)) * IH + row) * IW + col] * sqs[ic];
        float q = fminf(fmaxf(rintf(val), -128.f), 127.f);
        qa[(r * 33 + lv) * 256 + (ic ^ ((lv & 15) << 4))] = (char)(int)q;
    }
    __syncthreads();

    const char* wq8 = (const char*)(ws + WS_WQ8);

    // 9 balanced waves (32 MFMA each); taps folded into K; each output owned by ONE wave.
    // tap -> (par): 4->0; 3,5->1; 1,7->0; 0,2,6,8->1.  rows: taps<3 -> r1 else r0.
    if (wid == 0) {
        i32x16 acc[4] = {};
        const int taps[1] = {4};
        gemm_run<4, 1>(qa, wq8, taps, 0, lane, acc);
        #pragma unroll
        for (int n = 0; n < 4; ++n)
            dump_acc(buf0, acc[n], n * 32 + (lane & 31), 0, lane);
    } else if (wid <= 2) {
        i32x16 acc[2] = {};
        const int taps[2] = {3, 5};
        const int ocb = (wid - 1) * 64;
        gemm_run<2, 2>(qa, wq8, taps, ocb, lane, acc);
        #pragma unroll
        for (int n = 0; n < 2; ++n)
            dump_acc(buf0, acc[n], ocb + n * 32 + (lane & 31), 1, lane);
    } else if (wid <= 4) {
        i32x16 acc[2] = {};
        const int taps[2] = {1, 7};
        const int ocb = (wid - 3) * 64;
        gemm_run<2, 2>(qa, wq8, taps, ocb, lane, acc);
        #pragma unroll
        for (int n = 0; n < 2; ++n)
            dump_acc(buf1, acc[n], ocb + n * 32 + (lane & 31), 0, lane);
    } else {
        i32x16 acc[1] = {};
        const int taps[4] = {0, 2, 6, 8};
        const int ocb = (wid - 5) * 32;
        gemm_run<1, 4>(qa, wq8, taps, ocb, lane, acc);
        dump_acc(buf1, acc[0], ocb + (lane & 31), 1, lane);
    }
    __syncthreads();

    // store: 2 oh rows x 128 oc x 64 ow (this block's column half), float2, coalesced
    const float f = ws[WS_F];
    for (int i = tid; i < 8192; i += 576) {
        const int oh_sel = i >> 12;
        const int r2 = i & 4095;
        const int oc = r2 >> 5;
        const int o2 = r2 & 31;
        const int* bp = oh_sel ? buf1 : buf0;
        const int v0 = bp[oc * 66 + o2 * 2];
        const int v1 = bp[oc * 66 + o2 * 2 + 1];
        const float bv = bias[oc];
        float2 o;
        o.x = fmaf((float)v0, f, bv);
        o.y = fmaf((float)v1, f, bv);
        const int oh = 2 * u + oh_sel;
        *(float2*)(out + (((size_t)(b * OCH + oc)) * OH2 + oh) * OW2 + vh * 64 + o2 * 2) = o;
    }
}

extern "C" void kernel_launch(void* const* d_in, const int* in_sizes, int n_in,
                              void* d_out, int out_size, void* d_ws, size_t ws_size,
                              hipStream_t stream) {
    const float* x    = (const float*)d_in[0];
    const float* w    = (const float*)d_in[1];
    const float* bias = (const float*)d_in[2];
    float* ws  = (float*)d_ws;
    float* out = (float*)d_out;

    k_channel_scales<<<dim3(256, 8), 256, 0, stream>>>(x, w, ws);
    k_finalize<<<1, 256, 0, stream>>>(ws);
    k_quant_w<<<288, 256, 0, stream>>>(w, ws);
    k_conv<<<dim3(IH, 2, BSZ), 576, 0, stream>>>(x, bias, ws, out);
}